// Round 1
// baseline (343.423 us; speedup 1.0000x reference)
//
#include <hip/hip_runtime.h>

#define NLAB 30000
#define HID  1024
#define NB   256
#define NE   (NLAB - 1)

// ---------------------------------------------------------------------------
// block reduction: 256 threads = 4 waves of 64. Shuffle within wave, LDS across.
// Result valid on threadIdx.x == 0 only.
// ---------------------------------------------------------------------------
__device__ __forceinline__ float blockReduceSum(float v) {
#pragma unroll
    for (int off = 32; off > 0; off >>= 1)
        v += __shfl_down(v, off, 64);
    __shared__ float smem[4];
    const int lane = threadIdx.x & 63;
    const int wid  = threadIdx.x >> 6;
    if (lane == 0) smem[wid] = v;
    __syncthreads();
    float r = 0.f;
    if (threadIdx.x == 0) r = smem[0] + smem[1] + smem[2] + smem[3];
    return r;
}

// ws is re-poisoned to 0xAA before every timed launch -> must zero ourselves.
__global__ void init_kernel(double* acc) {
    acc[0] = 0.0; acc[1] = 0.0; acc[2] = 0.0;
}

// ---------------------------------------------------------------------------
// BCE: sum over B*N of softplus(l) - l*t   (mean applied in finalize)
// float4 vectorized grid-stride; 61.4 MB streamed.
// ---------------------------------------------------------------------------
__global__ void bce_kernel(const float4* __restrict__ lg,
                           const float4* __restrict__ tg,
                           double* __restrict__ acc) {
    const int total = NB * NLAB / 4;
    float s = 0.f;
    for (int i = blockIdx.x * blockDim.x + threadIdx.x; i < total;
         i += gridDim.x * blockDim.x) {
        float4 l = lg[i];
        float4 t = tg[i];
        s += fmaxf(l.x, 0.f) + log1pf(expf(-fabsf(l.x))) - l.x * t.x;
        s += fmaxf(l.y, 0.f) + log1pf(expf(-fabsf(l.y))) - l.y * t.y;
        s += fmaxf(l.z, 0.f) + log1pf(expf(-fabsf(l.z))) - l.z * t.z;
        s += fmaxf(l.w, 0.f) + log1pf(expf(-fabsf(l.w))) - l.w * t.w;
    }
    float r = blockReduceSum(s);
    if (threadIdx.x == 0) atomicAdd(&acc[0], (double)r);
}

// ---------------------------------------------------------------------------
// rec_reg: sum_e || params[p_e] - params[c_e] ||^2
// One block processes an edge per grid-stride step: 256 threads x float4 = 1024
// elements = HID exactly. Row reads are fully coalesced (4 KB contiguous rows).
// ---------------------------------------------------------------------------
__global__ void rec_kernel(const float4* __restrict__ p4,
                           const int* __restrict__ pidx,
                           const int* __restrict__ cidx,
                           double* __restrict__ acc) {
    float s = 0.f;
    for (int e = blockIdx.x; e < NE; e += gridDim.x) {
        const int p = pidx[e];
        const int c = cidx[e];
        const float4 a = p4[(size_t)p * (HID / 4) + threadIdx.x];
        const float4 b = p4[(size_t)c * (HID / 4) + threadIdx.x];
        const float dx = a.x - b.x, dy = a.y - b.y;
        const float dz = a.z - b.z, dw = a.w - b.w;
        s += dx * dx + dy * dy + dz * dz + dw * dw;
    }
    float r = blockReduceSum(s);
    if (threadIdx.x == 0) atomicAdd(&acc[1], (double)r);
}

// ---------------------------------------------------------------------------
// prob_reg: sum_{b,e} relu(sigmoid(l[b,c_e]) - sigmoid(l[b,p_e]))
// Grid-stride over B*E pairs, e fast within consecutive threads so index reads
// coalesce and gathers stay within one 120 KB logits row (L2-resident).
// ---------------------------------------------------------------------------
__global__ void prob_kernel(const float* __restrict__ lg,
                            const int* __restrict__ pidx,
                            const int* __restrict__ cidx,
                            double* __restrict__ acc) {
    const int total = NB * NE;
    float s = 0.f;
    for (int i = blockIdx.x * blockDim.x + threadIdx.x; i < total;
         i += gridDim.x * blockDim.x) {
        const int b = i / NE;
        const int e = i - b * NE;
        const int p = pidx[e];
        const int c = cidx[e];
        const float lp = lg[(size_t)b * NLAB + p];
        const float lc = lg[(size_t)b * NLAB + c];
        const float sp = 1.f / (1.f + expf(-lp));
        const float sc = 1.f / (1.f + expf(-lc));
        const float d = sc - sp;
        s += d > 0.f ? d : 0.f;
    }
    float r = blockReduceSum(s);
    if (threadIdx.x == 0) atomicAdd(&acc[2], (double)r);
}

__global__ void fin_kernel(const double* __restrict__ acc,
                           float* __restrict__ out) {
    const double bce = acc[0] * (1.0 / ((double)NB * (double)NLAB));
    out[0] = (float)(bce + 5e-5 * acc[1] + 1e-4 * acc[2]);
}

extern "C" void kernel_launch(void* const* d_in, const int* in_sizes, int n_in,
                              void* d_out, int out_size, void* d_ws, size_t ws_size,
                              hipStream_t stream) {
    const float* logits  = (const float*)d_in[0];
    const float* targets = (const float*)d_in[1];
    const float* params  = (const float*)d_in[2];
    const int*   pidx    = (const int*)d_in[3];
    const int*   cidx    = (const int*)d_in[4];
    double* acc = (double*)d_ws;
    float*  out = (float*)d_out;

    init_kernel<<<1, 1, 0, stream>>>(acc);
    bce_kernel<<<1920, 256, 0, stream>>>((const float4*)logits,
                                         (const float4*)targets, acc);
    rec_kernel<<<2048, 256, 0, stream>>>((const float4*)params, pidx, cidx, acc);
    prob_kernel<<<4096, 256, 0, stream>>>(logits, pidx, cidx, acc);
    fin_kernel<<<1, 1, 0, stream>>>(acc, out);
}

// Round 2
// 280.368 us; speedup vs baseline: 1.2249x; 1.2249x over previous
//
#include <hip/hip_runtime.h>

#define NLAB 30000
#define HID  1024
#define NB   256
#define NE   (NLAB - 1)

// ---------------------------------------------------------------------------
// block reduction for BLK threads (BLK/64 waves). Safe to call repeatedly.
// ---------------------------------------------------------------------------
template <int BLK>
__device__ __forceinline__ float blockReduceSum(float v) {
#pragma unroll
    for (int off = 32; off > 0; off >>= 1)
        v += __shfl_down(v, off, 64);
    __shared__ float smem[BLK / 64];
    const int lane = threadIdx.x & 63;
    const int wid  = threadIdx.x >> 6;
    __syncthreads();                 // protect smem reuse across calls
    if (lane == 0) smem[wid] = v;
    __syncthreads();
    float r = 0.f;
    if (threadIdx.x == 0) {
#pragma unroll
        for (int i = 0; i < BLK / 64; ++i) r += smem[i];
    }
    return r;
}

// ws is re-poisoned to 0xAA before every timed launch -> must zero ourselves.
__global__ void init_kernel(double* acc) {
    acc[0] = 0.0; acc[1] = 0.0; acc[2] = 0.0;
}

// ---------------------------------------------------------------------------
// Fused BCE + prob_reg. One block per batch row b:
//   phase 1: stream logits/targets row (float4), accumulate BCE partial,
//            write sigmoid(logit) into LDS (30000 floats = 117 KB).
//   phase 2: 29999 edges; d = sprob[c] - sprob[p] from LDS; relu-sum.
// Turns 15.4M random global gathers into LDS reads.
// ---------------------------------------------------------------------------
__global__ __launch_bounds__(1024, 1)
void row_kernel(const float4* __restrict__ lg4,
                const float4* __restrict__ tg4,
                const int* __restrict__ pidx,
                const int* __restrict__ cidx,
                double* __restrict__ acc) {
    __shared__ float sprob[NLAB];
    const int b   = blockIdx.x;
    const int tid = threadIdx.x;

    const float4* lrow = lg4 + (size_t)b * (NLAB / 4);
    const float4* trow = tg4 + (size_t)b * (NLAB / 4);

    float bces = 0.f;
    for (int i = tid; i < NLAB / 4; i += 1024) {
        const float4 l = lrow[i];
        const float4 t = trow[i];
        bces += fmaxf(l.x, 0.f) + log1pf(expf(-fabsf(l.x))) - l.x * t.x;
        bces += fmaxf(l.y, 0.f) + log1pf(expf(-fabsf(l.y))) - l.y * t.y;
        bces += fmaxf(l.z, 0.f) + log1pf(expf(-fabsf(l.z))) - l.z * t.z;
        bces += fmaxf(l.w, 0.f) + log1pf(expf(-fabsf(l.w))) - l.w * t.w;
        sprob[4 * i + 0] = 1.f / (1.f + expf(-l.x));
        sprob[4 * i + 1] = 1.f / (1.f + expf(-l.y));
        sprob[4 * i + 2] = 1.f / (1.f + expf(-l.z));
        sprob[4 * i + 3] = 1.f / (1.f + expf(-l.w));
    }
    __syncthreads();

    float ps = 0.f;
    for (int e = tid; e < NE; e += 1024) {
        const float d = sprob[cidx[e]] - sprob[pidx[e]];
        ps += d > 0.f ? d : 0.f;
    }

    const float rb = blockReduceSum<1024>(bces);
    const float rp = blockReduceSum<1024>(ps);
    if (threadIdx.x == 0) {
        atomicAdd(&acc[0], (double)rb);
        atomicAdd(&acc[2], (double)rp);
    }
}

// ---------------------------------------------------------------------------
// rec_reg: sum_e || params[p_e] - params[c_e] ||^2
// One block (256 thr x float4 = 1024 elem = HID) per edge per grid-stride step.
// ---------------------------------------------------------------------------
__global__ void rec_kernel(const float4* __restrict__ p4,
                           const int* __restrict__ pidx,
                           const int* __restrict__ cidx,
                           double* __restrict__ acc) {
    float s = 0.f;
    for (int e = blockIdx.x; e < NE; e += gridDim.x) {
        const int p = pidx[e];
        const int c = cidx[e];
        const float4 a = p4[(size_t)p * (HID / 4) + threadIdx.x];
        const float4 b = p4[(size_t)c * (HID / 4) + threadIdx.x];
        const float dx = a.x - b.x, dy = a.y - b.y;
        const float dz = a.z - b.z, dw = a.w - b.w;
        s += dx * dx + dy * dy + dz * dz + dw * dw;
    }
    const float r = blockReduceSum<256>(s);
    if (threadIdx.x == 0) atomicAdd(&acc[1], (double)r);
}

__global__ void fin_kernel(const double* __restrict__ acc,
                           float* __restrict__ out) {
    const double bce = acc[0] * (1.0 / ((double)NB * (double)NLAB));
    out[0] = (float)(bce + 5e-5 * acc[1] + 1e-4 * acc[2]);
}

extern "C" void kernel_launch(void* const* d_in, const int* in_sizes, int n_in,
                              void* d_out, int out_size, void* d_ws, size_t ws_size,
                              hipStream_t stream) {
    const float* logits  = (const float*)d_in[0];
    const float* targets = (const float*)d_in[1];
    const float* params  = (const float*)d_in[2];
    const int*   pidx    = (const int*)d_in[3];
    const int*   cidx    = (const int*)d_in[4];
    double* acc = (double*)d_ws;
    float*  out = (float*)d_out;

    init_kernel<<<1, 1, 0, stream>>>(acc);
    rec_kernel<<<2048, 256, 0, stream>>>((const float4*)params, pidx, cidx, acc);
    row_kernel<<<NB, 1024, 0, stream>>>((const float4*)logits,
                                        (const float4*)targets, pidx, cidx, acc);
    fin_kernel<<<1, 1, 0, stream>>>(acc, out);
}

// Round 3
// 261.344 us; speedup vs baseline: 1.3141x; 1.0728x over previous
//
#include <hip/hip_runtime.h>
#include <hip/hip_fp16.h>

#define NLAB 30000
#define HID  1024
#define NB   256
#define NE   (NLAB - 1)

#define ROW_BLOCKS NB        // one per batch row
#define REC_BLOCKS 512       // 2 per CU
#define TOT_BLOCKS (ROW_BLOCKS + REC_BLOCKS)
#define EDGES_PER_SWEEP (REC_BLOCKS * 4)   // 4 edge-groups of 256 thr per block

// float block reduce, BLK threads (BLK/64 waves)
template <int BLK>
__device__ __forceinline__ float blockReduceSum(float v) {
#pragma unroll
    for (int off = 32; off > 0; off >>= 1)
        v += __shfl_down(v, off, 64);
    __shared__ float smem[BLK / 64];
    const int lane = threadIdx.x & 63;
    const int wid  = threadIdx.x >> 6;
    __syncthreads();
    if (lane == 0) smem[wid] = v;
    __syncthreads();
    float r = 0.f;
    if (threadIdx.x == 0) {
#pragma unroll
        for (int i = 0; i < BLK / 64; ++i) r += smem[i];
    }
    return r;
}

// double block reduce for the finalize kernel (256 threads)
__device__ __forceinline__ double blockReduceSumD256(double v) {
#pragma unroll
    for (int off = 32; off > 0; off >>= 1)
        v += __shfl_down(v, off, 64);
    __shared__ double smem[4];
    const int lane = threadIdx.x & 63;
    const int wid  = threadIdx.x >> 6;
    __syncthreads();
    if (lane == 0) smem[wid] = v;
    __syncthreads();
    double r = 0.0;
    if (threadIdx.x == 0) r = smem[0] + smem[1] + smem[2] + smem[3];
    return r;
}

// ---------------------------------------------------------------------------
// Fused kernel, block-specialized:
//   blocks [0, NB):            row work — BCE partial + fp16 sigmoid row in
//                              LDS (60 KB) + prob_reg edge lookups from LDS.
//   blocks [NB, NB+REC_BLOCKS): rec work — 4 edge-groups x 256 threads,
//                              float4 row gathers, ||diff||^2 partial.
// Each block writes its partials to ws slots (overwrites poison; no init).
// ws layout: [0..TOT) bce | [TOT..2*TOT) rec | [2*TOT..3*TOT) prob, doubles.
// ---------------------------------------------------------------------------
__global__ __launch_bounds__(1024, 2)
void fused_kernel(const float4* __restrict__ lg4,
                  const float4* __restrict__ tg4,
                  const float4* __restrict__ p4,
                  const int* __restrict__ pidx,
                  const int* __restrict__ cidx,
                  double* __restrict__ slots) {
    __shared__ __half sprob[NLAB];
    const int tid = threadIdx.x;
    const int bid = blockIdx.x;

    float bces = 0.f, recs = 0.f, ps = 0.f;

    if (bid < ROW_BLOCKS) {
        // ---- row work: BCE + sigmoid staging ----
        const int b = bid;
        const float4* lrow = lg4 + (size_t)b * (NLAB / 4);
        const float4* trow = tg4 + (size_t)b * (NLAB / 4);
        for (int i = tid; i < NLAB / 4; i += 1024) {
            const float4 l = lrow[i];
            const float4 t = trow[i];
            bces += fmaxf(l.x, 0.f) + log1pf(__expf(-fabsf(l.x))) - l.x * t.x;
            bces += fmaxf(l.y, 0.f) + log1pf(__expf(-fabsf(l.y))) - l.y * t.y;
            bces += fmaxf(l.z, 0.f) + log1pf(__expf(-fabsf(l.z))) - l.z * t.z;
            bces += fmaxf(l.w, 0.f) + log1pf(__expf(-fabsf(l.w))) - l.w * t.w;
            sprob[4 * i + 0] = __float2half(1.f / (1.f + __expf(-l.x)));
            sprob[4 * i + 1] = __float2half(1.f / (1.f + __expf(-l.y)));
            sprob[4 * i + 2] = __float2half(1.f / (1.f + __expf(-l.z)));
            sprob[4 * i + 3] = __float2half(1.f / (1.f + __expf(-l.w)));
        }
        __syncthreads();
        // ---- prob_reg from LDS ----
        for (int e = tid; e < NE; e += 1024) {
            const float d = __half2float(sprob[cidx[e]]) -
                            __half2float(sprob[pidx[e]]);
            ps += d > 0.f ? d : 0.f;
        }
    } else {
        // ---- rec work ----
        const int recId = bid - ROW_BLOCKS;          // 0..REC_BLOCKS-1
        const int g     = tid >> 8;                  // edge group 0..3
        const int lg_   = tid & 255;                 // lane in group
        for (int e = recId * 4 + g; e < NE; e += EDGES_PER_SWEEP) {
            const int p = pidx[e];
            const int c = cidx[e];
            const float4 a = p4[(size_t)p * (HID / 4) + lg_];
            const float4 b = p4[(size_t)c * (HID / 4) + lg_];
            const float dx = a.x - b.x, dy = a.y - b.y;
            const float dz = a.z - b.z, dw = a.w - b.w;
            recs += dx * dx + dy * dy + dz * dz + dw * dw;
        }
    }

    const float rb = blockReduceSum<1024>(bces);
    const float rr = blockReduceSum<1024>(recs);
    const float rp = blockReduceSum<1024>(ps);
    if (tid == 0) {
        slots[bid]                  = (double)rb;
        slots[TOT_BLOCKS + bid]     = (double)rr;
        slots[2 * TOT_BLOCKS + bid] = (double)rp;
    }
}

// finalize: sum the 3 slot arrays, combine, write scalar
__global__ void fin_kernel(const double* __restrict__ slots,
                           float* __restrict__ out) {
    double sb = 0.0, sr = 0.0, sp = 0.0;
    for (int i = threadIdx.x; i < TOT_BLOCKS; i += 256) {
        sb += slots[i];
        sr += slots[TOT_BLOCKS + i];
        sp += slots[2 * TOT_BLOCKS + i];
    }
    sb = blockReduceSumD256(sb);
    sr = blockReduceSumD256(sr);
    sp = blockReduceSumD256(sp);
    if (threadIdx.x == 0) {
        const double bce = sb * (1.0 / ((double)NB * (double)NLAB));
        out[0] = (float)(bce + 5e-5 * sr + 1e-4 * sp);
    }
}

extern "C" void kernel_launch(void* const* d_in, const int* in_sizes, int n_in,
                              void* d_out, int out_size, void* d_ws, size_t ws_size,
                              hipStream_t stream) {
    const float* logits  = (const float*)d_in[0];
    const float* targets = (const float*)d_in[1];
    const float* params  = (const float*)d_in[2];
    const int*   pidx    = (const int*)d_in[3];
    const int*   cidx    = (const int*)d_in[4];
    double* slots = (double*)d_ws;
    float*  out   = (float*)d_out;

    fused_kernel<<<TOT_BLOCKS, 1024, 0, stream>>>(
        (const float4*)logits, (const float4*)targets, (const float4*)params,
        pidx, cidx, slots);
    fin_kernel<<<1, 256, 0, stream>>>(slots, out);
}